// Round 2
// baseline (174.228 us; speedup 1.0000x reference)
//
#include <hip/hip_runtime.h>

// MoE_52037823758984: out[i] = x[i] @ W_{route[i]}^T + b_{route[i]}
// N = 2,097,152 tokens, D = 10, all f32 (route int32).
//
// R8 = R7 resubmitted verbatim (R7 bench died on container acquire --
// "MI355X container failed twice" -- infra, not kernel; no counters came
// back, so the R7 experiment has not actually run yet).
//
// R7 = R6's proven shell + depth-2 per-wave software pipeline.
//   Diagnosis: R6 at 50.5us kernel had VALUBusy 13%, HBM 41% of achievable,
//   occupancy 52% -> latency-bound, not BW-bound. Each wave was a serial
//   one-shot {load -> vmcnt(0) -> compute -> store}; outstanding-load duty
//   cycle too low, bursty issue underfeeds the HBM queue.
//   Fix: each wave processes TWO 128-row chunks; chunk i+1's global loads
//   are issued (into a second register buffer) BEFORE chunk i's
//   LDS/compute/store phase, so loads stay in flight under compute.
//   Register staging (not global_load_lds) keeps all waitcnt insertion
//   compiler-precise -- the compiler waits only on the regs it needs,
//   leaving the prefetch outstanding.
// Unchanged proven pieces (R2/R4/R5):
//   - LDS round-trip BOTH directions; global loads/stores lane-contiguous
//     1 KB/instruction. nt ONLY on fully-coalesced stores (R4-clean;
//     R5 proved nt+strided amplifies writes 2.65x).
//   - Packed f32 math: (row0,row1) in float2 accumulators -> v_pk_fma_f32.
//   - 20 KB LDS/block, 256 threads; block turnover still provides
//     cross-wave staggering (2048 blocks, 8 resident/CU).

#define BLOCK 256
#define D 10
#define CHUNK_ROWS 128                 // rows per wave per chunk
#define F4_PER_CHUNK 320               // 128*10/4 = 5 f4 per lane
#define NCHUNK 2                       // chunks per wave (depth-2 pipeline)
#define ROWS_PER_WAVE (CHUNK_ROWS * NCHUNK)           // 256
#define ROWS_PER_BLOCK (ROWS_PER_WAVE * (BLOCK / 64)) // 1024

typedef float f4 __attribute__((ext_vector_type(4)));
typedef float f2 __attribute__((ext_vector_type(2)));

__device__ __forceinline__ void load_chunk(const float* __restrict__ x,
                                           const int* __restrict__ route,
                                           long long cbase, int lane,
                                           f4 (&bx)[5], int2& rt)
{
    const f4* __restrict__ xv = (const f4*)(x + cbase * D);
    #pragma unroll
    for (int j = 0; j < 5; ++j)
        bx[j] = xv[j * 64 + lane];
    rt = ((const int2*)(route + cbase))[lane];
}

__device__ __forceinline__ void process_chunk(
    const float* __restrict__ x,
    const float* __restrict__ W1, const float* __restrict__ b1,
    const float* __restrict__ W2, const float* __restrict__ b2,
    const int* __restrict__ route,
    float* __restrict__ out,
    f4* __restrict__ wlds, int lane, long long cbase,
    f4 (&bxc)[5], int2 rtc,
    bool prefetch, f4 (&bxn)[5], int2& rtn)
{
    // ---- issue next chunk's loads FIRST: they fly under this compute ----
    if (prefetch)
        load_chunk(x, route, cbase + CHUNK_ROWS, lane, bxn, rtn);

    // ---- LDS transpose in (linear copy re-partitions rows to lanes) ----
    // wave_barrier: keep these writes behind the previous chunk's output
    // ds_reads (same LDS addresses; scheduling fence only, no HW op).
    __builtin_amdgcn_wave_barrier();
    #pragma unroll
    for (int j = 0; j < 5; ++j)
        wlds[j * 64 + lane] = bxc[j];
    __builtin_amdgcn_wave_barrier();

    // lane's 2 rows (20 consecutive floats), conflict-free b128 reads
    float xf[2 * D];
    #pragma unroll
    for (int j = 0; j < 5; ++j) {
        f4 t = wlds[lane * 5 + j];
        xf[4 * j + 0] = t.x; xf[4 * j + 1] = t.y;
        xf[4 * j + 2] = t.z; xf[4 * j + 3] = t.w;
    }

    // row-pair vectors: xp[k] = (row0[k], row1[k])
    f2 xp[D];
    #pragma unroll
    for (int k = 0; k < D; ++k)
        xp[k] = (f2){xf[k], xf[D + k]};

    // ---- packed MLP: both experts, route-select ----
    float o0[D], o1[D];
    #pragma unroll
    for (int j = 0; j < D; ++j) {
        f2 a0 = (f2){b1[j], b1[j]};
        f2 a1 = (f2){b2[j], b2[j]};
        #pragma unroll
        for (int k = 0; k < D; ++k) {
            const float w1 = W1[j * D + k];
            const float w2 = W2[j * D + k];
            a0 = __builtin_elementwise_fma(xp[k], (f2){w1, w1}, a0);
            a1 = __builtin_elementwise_fma(xp[k], (f2){w2, w2}, a1);
        }
        o0[j] = rtc.x ? a1.x : a0.x;
        o1[j] = rtc.y ? a1.y : a0.y;
    }

    // ---- LDS transpose out (lane-private slots, in-order) ----
    __builtin_amdgcn_wave_barrier();  // keep behind the input ds_reads
    {
        f4 t0 = (f4){o0[0], o0[1], o0[2], o0[3]};
        f4 t1 = (f4){o0[4], o0[5], o0[6], o0[7]};
        f4 t2 = (f4){o0[8], o0[9], o1[0], o1[1]};
        f4 t3 = (f4){o1[2], o1[3], o1[4], o1[5]};
        f4 t4 = (f4){o1[6], o1[7], o1[8], o1[9]};
        wlds[lane * 5 + 0] = t0;
        wlds[lane * 5 + 1] = t1;
        wlds[lane * 5 + 2] = t2;
        wlds[lane * 5 + 3] = t3;
        wlds[lane * 5 + 4] = t4;
    }
    __builtin_amdgcn_wave_barrier();

    // ---- coalesced nontemporal stores (1 KB/instr, proven clean) ----
    f4* __restrict__ ov = (f4*)(out + cbase * D);
    #pragma unroll
    for (int j = 0; j < 5; ++j) {
        f4 t = wlds[j * 64 + lane];
        __builtin_nontemporal_store(t, &ov[j * 64 + lane]);
    }
}

__global__ __launch_bounds__(BLOCK) void moe_kernel(
    const float* __restrict__ x,
    const float* __restrict__ W1,
    const float* __restrict__ b1,
    const float* __restrict__ W2,
    const float* __restrict__ b2,
    const int*   __restrict__ route,
    float*       __restrict__ out,
    int n)
{
    __shared__ f4 lds[(BLOCK / 64) * F4_PER_CHUNK];  // 20 KB

    const int lane = threadIdx.x & 63;
    const int wave = threadIdx.x >> 6;
    f4* __restrict__ wlds = lds + wave * F4_PER_CHUNK;

    const long long wavebase =
        ((long long)blockIdx.x * (BLOCK / 64) + wave) * ROWS_PER_WAVE;

    if (wavebase + ROWS_PER_WAVE <= n) {
        f4 bxA[5], bxB[5];
        int2 rtA, rtB;

        // prologue: chunk 0 into A
        load_chunk(x, route, wavebase, lane, bxA, rtA);

        // chunk 0: compute A while B's loads fly
        process_chunk(x, W1, b1, W2, b2, route, out, wlds, lane,
                      wavebase, bxA, rtA,
                      /*prefetch=*/true, bxB, rtB);
        // chunk 1: loads already landed during chunk 0's compute
        process_chunk(x, W1, b1, W2, b2, route, out, wlds, lane,
                      wavebase + CHUNK_ROWS, bxB, rtB,
                      /*prefetch=*/false, bxA, rtA);
    } else {
        // ---------- tail path (not hit for N=2097152) ----------
        for (int r = 0; r < ROWS_PER_WAVE / 64; ++r) {
            const long long row = wavebase + (long long)lane * (ROWS_PER_WAVE / 64) + r;
            if (row < n) {
                const int sel = route[row];
                for (int j = 0; j < D; ++j) {
                    float y0 = b1[j];
                    float y1 = b2[j];
                    for (int k = 0; k < D; ++k) {
                        const float xk = x[row * D + k];
                        y0 = fmaf(xk, W1[j * D + k], y0);
                        y1 = fmaf(xk, W2[j * D + k], y1);
                    }
                    out[row * D + j] = sel ? y1 : y0;
                }
            }
        }
    }
}

extern "C" void kernel_launch(void* const* d_in, const int* in_sizes, int n_in,
                              void* d_out, int out_size, void* d_ws, size_t ws_size,
                              hipStream_t stream) {
    const float* x     = (const float*)d_in[0];
    const float* W1    = (const float*)d_in[1];
    const float* b1    = (const float*)d_in[2];
    const float* W2    = (const float*)d_in[3];
    const float* b2    = (const float*)d_in[4];
    const int*   route = (const int*)d_in[5];
    float*       out   = (float*)d_out;

    const int n = in_sizes[5];  // N tokens (route length)
    const int blocks = (n + ROWS_PER_BLOCK - 1) / ROWS_PER_BLOCK;  // 2048

    moe_kernel<<<blocks, BLOCK, 0, stream>>>(x, W1, b1, W2, b2, route, out, n);
}

// Round 3
// 166.342 us; speedup vs baseline: 1.0474x; 1.0474x over previous
//
#include <hip/hip_runtime.h>

// MoE_52037823758984: out[i] = x[i] @ W_{route[i]}^T + b_{route[i]}
// N = 2,097,152 tokens, D = 10, all f32 (route int32).
//
// R9 = depth-2 pipeline with LDS staging via global_load_lds (VGPR-free).
//   R7/R8 post-mortem: register-staged prefetch validated the mechanism
//   (VALUBusy 13->24%) but VGPR 28->68 crossed the 64-reg cliff ->
//   occupancy 52->25% -> net regression (50.5->61us). Fix: stage through
//   LDS with __builtin_amdgcn_global_load_lds (no dest registers, no
//   VGPR cost), double-buffered per wave. This also deletes the LDS-in
//   transpose writes (gll writes LDS directly in the exact linear layout
//   the ds_reads expect: uniform base + lane*16).
//   All staged data (x AND route) flows through gll -> the hot path has
//   ZERO VMEM loads with register destinations -> all vmcnt bookkeeping
//   is manual and precise:
//     issue route(1) + c0(5) + c1(5)       // 11 outstanding
//     vmcnt(5)  -> oldest 6 (route+c0) landed; c1 still flying
//     compute c0 (ds_read/VALU only)       // c1 hides under this
//     vmcnt(0)  -> c1 landed (stores not yet issued: waited sets are
//                  pure-gll, no store-retire-order dependence)
//     nt-store c0; compute c1; nt-store c1 // stores never waited on
//   asm volatile + "memory" clobber + sched_barrier(0) fence the ds_reads
//   behind each wait (compiler does not model gll->LDS aliasing).
// Unchanged proven pieces (R2/R4/R5/R6):
//   - coalesced 1KB/instr global loads & stores; nt ONLY on coalesced
//     stores (R4-clean; R5: nt+strided amplifies writes 2.65x).
//   - packed f32 math: (row0,row1) in float2 -> v_pk_fma_f32.
//   - conflict-free b128 LDS reads at lane*80B (R6: 0 bank conflicts).
//   - BLOCK=128 (2 waves), 22KB LDS -> 7 blocks/CU = 14 waves/CU;
//     grid 4096 blocks (R6-proven dispatch rate, ~2.3x turnover).

#define BLOCK 128
#define D 10
#define CHUNK_ROWS 128                 // rows per wave per chunk
#define NCHUNK 2                       // depth-2 pipeline
#define ROWS_PER_WAVE (CHUNK_ROWS * NCHUNK)           // 256
#define WAVES_PER_BLOCK (BLOCK / 64)                  // 2
#define ROWS_PER_BLOCK (ROWS_PER_WAVE * WAVES_PER_BLOCK) // 512
#define F4_PER_CHUNK 320               // 128 rows * 10 f / 4

typedef float f4 __attribute__((ext_vector_type(4)));
typedef float f2 __attribute__((ext_vector_type(2)));

// global_load_lds: per-lane GLOBAL src, wave-uniform LDS dst (+lane*16).
#define GLL16(gsrc, ldst)                                                   \
    __builtin_amdgcn_global_load_lds(                                       \
        (const __attribute__((address_space(1))) void*)(gsrc),              \
        (__attribute__((address_space(3))) void*)(ldst), 16, 0, 0)

__global__ __launch_bounds__(BLOCK) void moe_kernel(
    const float* __restrict__ x,
    const float* __restrict__ W1,
    const float* __restrict__ b1,
    const float* __restrict__ W2,
    const float* __restrict__ b2,
    const int*   __restrict__ route,
    float*       __restrict__ out,
    int n)
{
    // per wave: 2 x-buffers (5KB each) + 1 route buffer (1KB, both chunks)
    __shared__ f4  xbuf[WAVES_PER_BLOCK][NCHUNK][F4_PER_CHUNK];  // 20 KB
    __shared__ int rbuf[WAVES_PER_BLOCK][ROWS_PER_WAVE];         //  2 KB

    const int lane = threadIdx.x & 63;
    const int wave = threadIdx.x >> 6;
    f4*  __restrict__ xb0 = xbuf[wave][0];
    f4*  __restrict__ xb1 = xbuf[wave][1];
    int* __restrict__ rb  = rbuf[wave];

    const long long wavebase =
        ((long long)blockIdx.x * WAVES_PER_BLOCK + wave) * ROWS_PER_WAVE;

    if (wavebase + ROWS_PER_WAVE <= n) {
        // ---------------- issue ALL staging loads upfront ----------------
        // route for BOTH chunks: 256 ints = 64 lanes x 16B, one gll.
        GLL16(route + wavebase + 4 * lane, rb);
        // x chunk0 then chunk1: 5 gll each, 1KB/instr, lane-contiguous.
        const float* xs0 = x + wavebase * D;
        const float* xs1 = x + (wavebase + CHUNK_ROWS) * D;
        #pragma unroll
        for (int j = 0; j < 5; ++j)
            GLL16(xs0 + j * 256 + 4 * lane, xb0 + j * 64);
        #pragma unroll
        for (int j = 0; j < 5; ++j)
            GLL16(xs1 + j * 256 + 4 * lane, xb1 + j * 64);

        f4 st0[5], st1[5];  // store-staging regs for chunk0/1 outputs

        #pragma unroll
        for (int p = 0; p < NCHUNK; ++p) {
            f4* __restrict__ xb = p ? xb1 : xb0;

            // ---- wait for this chunk's staged data (counted, manual) ----
            if (p == 0) {
                // oldest 6 = route + c0; c1's 5 stay in flight under c0.
                asm volatile("s_waitcnt vmcnt(5)" ::: "memory");
            } else {
                // only c1's glls outstanding (c0 stores not yet issued).
                asm volatile("s_waitcnt vmcnt(0)" ::: "memory");
            }
            __builtin_amdgcn_sched_barrier(0);

            // ---- lane's 2 rows (20 consecutive floats), b128 reads ----
            float xf[2 * D];
            #pragma unroll
            for (int j = 0; j < 5; ++j) {
                f4 t = xb[lane * 5 + j];
                xf[4 * j + 0] = t.x; xf[4 * j + 1] = t.y;
                xf[4 * j + 2] = t.z; xf[4 * j + 3] = t.w;
            }
            const int2 rt = *(const int2*)(rb + p * CHUNK_ROWS + 2 * lane);

            // row-pair vectors: xp[k] = (row0[k], row1[k])
            f2 xp[D];
            #pragma unroll
            for (int k = 0; k < D; ++k)
                xp[k] = (f2){xf[k], xf[D + k]};

            // ---- packed MLP: both experts, route-select ----
            float o0[D], o1[D];
            #pragma unroll
            for (int j = 0; j < D; ++j) {
                f2 a0 = (f2){b1[j], b1[j]};
                f2 a1 = (f2){b2[j], b2[j]};
                #pragma unroll
                for (int k = 0; k < D; ++k) {
                    const float w1 = W1[j * D + k];
                    const float w2 = W2[j * D + k];
                    a0 = __builtin_elementwise_fma(xp[k], (f2){w1, w1}, a0);
                    a1 = __builtin_elementwise_fma(xp[k], (f2){w2, w2}, a1);
                }
                o0[j] = rt.x ? a1.x : a0.x;
                o1[j] = rt.y ? a1.y : a0.y;
            }

            // ---- LDS transpose out (reuse this chunk's x buffer) ----
            __builtin_amdgcn_wave_barrier();  // behind the input ds_reads
            {
                wlds_write:
                f4 t0 = (f4){o0[0], o0[1], o0[2], o0[3]};
                f4 t1 = (f4){o0[4], o0[5], o0[6], o0[7]};
                f4 t2 = (f4){o0[8], o0[9], o1[0], o1[1]};
                f4 t3 = (f4){o1[2], o1[3], o1[4], o1[5]};
                f4 t4 = (f4){o1[6], o1[7], o1[8], o1[9]};
                xb[lane * 5 + 0] = t0;
                xb[lane * 5 + 1] = t1;
                xb[lane * 5 + 2] = t2;
                xb[lane * 5 + 3] = t3;
                xb[lane * 5 + 4] = t4;
            }
            __builtin_amdgcn_wave_barrier();

            // read back coalesced rows into store-staging regs
            f4* st = p ? st1 : st0;
            #pragma unroll
            for (int j = 0; j < 5; ++j)
                st[j] = xb[j * 64 + lane];
            // chunk0's stores are DEFERRED until after the vmcnt(0) so the
            // waited sets stay pure-gll (see header); issue them now for
            // p==1 path ordering below.
            if (p == 1) break;
        }

        // ---- coalesced nontemporal stores (1KB/instr, proven clean) ----
        // c0 stores were issued after vmcnt(0) inside iteration p==1's
        // wait; emit both chunks' stores here, never waited on.
        {
            f4* __restrict__ ov0 = (f4*)(out + wavebase * D);
            f4* __restrict__ ov1 = (f4*)(out + (wavebase + CHUNK_ROWS) * D);
            #pragma unroll
            for (int j = 0; j < 5; ++j)
                __builtin_nontemporal_store(st0[j], &ov0[j * 64 + lane]);
            #pragma unroll
            for (int j = 0; j < 5; ++j)
                __builtin_nontemporal_store(st1[j], &ov1[j * 64 + lane]);
        }
    } else {
        // ---------- tail path (not hit for N=2097152) ----------
        for (int r = 0; r < ROWS_PER_WAVE / 64; ++r) {
            const long long row =
                wavebase + (long long)lane * (ROWS_PER_WAVE / 64) + r;
            if (row < n) {
                const int sel = route[row];
                for (int j = 0; j < D; ++j) {
                    float y0 = b1[j];
                    float y1 = b2[j];
                    for (int k = 0; k < D; ++k) {
                        const float xk = x[row * D + k];
                        y0 = fmaf(xk, W1[j * D + k], y0);
                        y1 = fmaf(xk, W2[j * D + k], y1);
                    }
                    out[row * D + j] = sel ? y1 : y0;
                }
            }
        }
    }
}

extern "C" void kernel_launch(void* const* d_in, const int* in_sizes, int n_in,
                              void* d_out, int out_size, void* d_ws, size_t ws_size,
                              hipStream_t stream) {
    const float* x     = (const float*)d_in[0];
    const float* W1    = (const float*)d_in[1];
    const float* b1    = (const float*)d_in[2];
    const float* W2    = (const float*)d_in[3];
    const float* b2    = (const float*)d_in[4];
    const int*   route = (const int*)d_in[5];
    float*       out   = (float*)d_out;

    const int n = in_sizes[5];  // N tokens (route length)
    const int blocks = (n + ROWS_PER_BLOCK - 1) / ROWS_PER_BLOCK;  // 4096

    moe_kernel<<<blocks, BLOCK, 0, stream>>>(x, W1, b1, W2, b2, route, out, n);
}

// Round 4
// 163.262 us; speedup vs baseline: 1.0672x; 1.0189x over previous
//
#include <hip/hip_runtime.h>

// MoE_52037823758984: out[i] = x[i] @ W_{route[i]}^T + b_{route[i]}
// N = 2,097,152 tokens, D = 10, all f32 (route int32).
//
// R10 = R6's proven 50.5us shell with ONE change: plain stores instead of
// nontemporal.
//   R7-R9 post-mortem: per-wave pipelining (reg-staged AND gll-staged) is
//   a dead end -- every variant paid its buffers in occupancy (32 -> 14-16
//   waves/CU cap) and lost net (50.5 -> 61-62us). Occupancy hides latency
//   more cheaply than in-wave pipelines here.
//   New theory: working set x(84MB)+out(84MB)+route(8MB) = 176MB fits in
//   the 256MB Infinity Cache, yet counters show 45MB HBM FETCH (half of x
//   evicted every iter) and a full 82MB HBM WRITE. The nt hint makes the
//   store stream no-allocate: out never becomes L3-resident, the 82MB
//   write drain lands in the kernel's critical path, and its cache
//   pressure evicts half of x. nt was adopted (R4/R5) to fix STRIDED
//   store amplification; it was never A/B'd on the coalesced path.
//   Plain write-back stores should let L3 absorb the writes and keep x
//   resident -> reads at L3 speed, writes retired at cache speed.
// Unchanged proven pieces (R2/R4/R5/R6):
//   - LDS round-trip BOTH directions; global loads and stores are
//     lane-contiguous 1 KB/instruction.
//   - Packed f32 math: (row0,row1) in float2 accumulators -> v_pk_fma_f32.
//   - 4096 blocks x 256, one 512-row chunk per block; block turnover is
//     the pipelining (VGPR 28 / 20KB LDS -> full 32-waves/CU cap).

#define BLOCK 256
#define D 10
#define WAVE_ROWS 128              // rows per wave
#define F4_PER_WAVE 320            // 128*10/4
#define ROWS_PER_BLOCK 512         // 4 waves

typedef float f4 __attribute__((ext_vector_type(4)));
typedef float f2 __attribute__((ext_vector_type(2)));

__global__ __launch_bounds__(BLOCK) void moe_kernel(
    const float* __restrict__ x,
    const float* __restrict__ W1,
    const float* __restrict__ b1,
    const float* __restrict__ W2,
    const float* __restrict__ b2,
    const int*   __restrict__ route,
    float*       __restrict__ out,
    int n)
{
    __shared__ f4 lds[(BLOCK / 64) * F4_PER_WAVE];  // 20 KB

    const int lane = threadIdx.x & 63;
    const int wave = threadIdx.x >> 6;
    f4* __restrict__ wlds = lds + wave * F4_PER_WAVE;

    const long long rowbase =
        ((long long)blockIdx.x * (BLOCK / 64) + wave) * WAVE_ROWS;

    if (rowbase + WAVE_ROWS <= n) {
        // ---------- coalesced loads: 5 f4/lane + route int2 ----------
        const f4* __restrict__ xv = (const f4*)(x + rowbase * D);
        f4 bx[5];
        #pragma unroll
        for (int j = 0; j < 5; ++j)
            bx[j] = xv[j * 64 + lane];
        const int2 rt = ((const int2*)(route + rowbase))[lane];

        // ---------- LDS transpose in ----------
        #pragma unroll
        for (int j = 0; j < 5; ++j)
            wlds[j * 64 + lane] = bx[j];
        __builtin_amdgcn_wave_barrier();

        // lane's 2 rows (20 consecutive floats), conflict-free b128 reads
        float xf[2 * D];
        #pragma unroll
        for (int j = 0; j < 5; ++j) {
            f4 t = wlds[lane * 5 + j];
            xf[4 * j + 0] = t.x; xf[4 * j + 1] = t.y;
            xf[4 * j + 2] = t.z; xf[4 * j + 3] = t.w;
        }

        // row-pair vectors: xp[k] = (row0[k], row1[k])
        f2 xp[D];
        #pragma unroll
        for (int k = 0; k < D; ++k)
            xp[k] = (f2){xf[k], xf[D + k]};

        // ---------- packed MLP: both experts, route-select ----------
        float o0[D], o1[D];
        #pragma unroll
        for (int j = 0; j < D; ++j) {
            f2 a0 = (f2){b1[j], b1[j]};
            f2 a1 = (f2){b2[j], b2[j]};
            #pragma unroll
            for (int k = 0; k < D; ++k) {
                const float w1 = W1[j * D + k];
                const float w2 = W2[j * D + k];
                a0 = __builtin_elementwise_fma(xp[k], (f2){w1, w1}, a0);
                a1 = __builtin_elementwise_fma(xp[k], (f2){w2, w2}, a1);
            }
            o0[j] = rt.x ? a1.x : a0.x;
            o1[j] = rt.y ? a1.y : a0.y;
        }

        // ---------- LDS transpose out (lane-private slots, in-order) ----
        __builtin_amdgcn_wave_barrier();  // keep behind the ds_reads above
        {
            f4 t0 = (f4){o0[0], o0[1], o0[2], o0[3]};
            f4 t1 = (f4){o0[4], o0[5], o0[6], o0[7]};
            f4 t2 = (f4){o0[8], o0[9], o1[0], o1[1]};
            f4 t3 = (f4){o1[2], o1[3], o1[4], o1[5]};
            f4 t4 = (f4){o1[6], o1[7], o1[8], o1[9]};
            wlds[lane * 5 + 0] = t0;
            wlds[lane * 5 + 1] = t1;
            wlds[lane * 5 + 2] = t2;
            wlds[lane * 5 + 3] = t3;
            wlds[lane * 5 + 4] = t4;
        }
        __builtin_amdgcn_wave_barrier();

        // ---------- coalesced PLAIN stores (1 KB/instr) ----------
        // R10 change: no nontemporal hint. out (84MB) fits in the 256MB
        // L3 alongside x; write-back lets the cache absorb the stream and
        // keeps x resident across bench iterations.
        f4* __restrict__ ov = (f4*)(out + rowbase * D);
        #pragma unroll
        for (int j = 0; j < 5; ++j)
            ov[j * 64 + lane] = wlds[j * 64 + lane];
    } else {
        // ---------- tail path (not hit for N=2097152) ----------
        for (int r = 0; r < 2; ++r) {
            const long long row = rowbase + lane * 2 + r;
            if (row < n) {
                const int sel = route[row];
                for (int j = 0; j < D; ++j) {
                    float y0 = b1[j];
                    float y1 = b2[j];
                    for (int k = 0; k < D; ++k) {
                        const float xk = x[row * D + k];
                        y0 = fmaf(xk, W1[j * D + k], y0);
                        y1 = fmaf(xk, W2[j * D + k], y1);
                    }
                    out[row * D + j] = sel ? y1 : y0;
                }
            }
        }
    }
}

extern "C" void kernel_launch(void* const* d_in, const int* in_sizes, int n_in,
                              void* d_out, int out_size, void* d_ws, size_t ws_size,
                              hipStream_t stream) {
    const float* x     = (const float*)d_in[0];
    const float* W1    = (const float*)d_in[1];
    const float* b1    = (const float*)d_in[2];
    const float* W2    = (const float*)d_in[3];
    const float* b2    = (const float*)d_in[4];
    const int*   route = (const int*)d_in[5];
    float*       out   = (float*)d_out;

    const int n = in_sizes[5];  // N tokens (route length)
    const int blocks = (n + ROWS_PER_BLOCK - 1) / ROWS_PER_BLOCK;  // 4096

    moe_kernel<<<blocks, BLOCK, 0, stream>>>(x, W1, b1, W2, b2, route, out, n);
}